// Round 9
// baseline (167.695 us; speedup 1.0000x reference)
//
#include <hip/hip_runtime.h>

// EdgeConv, algebraically simplified:
//   out[p,o] = sum_c (t[p,c]/K - x[p,c])*W[o,c] + sum_c x[p,c]*W[o,64+c] + b[o]
//   t[p,c]   = sum_{kk=0..19} flat[p, 20c+kk],  flat[p,j] = x[b, adj[p,j>>6], j&63]
// R12 = R11 + NONTEMPORAL gather loads (single-variable experiment; resubmit
//     after infra failure). Evidence ladder: R8b(21 DMA insts)=R10(11 DMA insts)
//     =R11(3 dwordx4 insts) = 63-66us -- the wall is ~7cyc per 64B scattered
//     segment per CU, with latency fully hidden and all pipes idle. Candidate
//     mechanisms: vL1 miss-allocation rate (gathers always miss the 32KB L1;
//     4MB working set) vs deeper fabric/L2-tag rate. nt loads skip L1
//     allocation -> if (1), time drops to ~35-45us; if FETCH explodes, nt also
//     broke L2 residency (revert); if flat, wall is fabric-side. Everything
//     else verbatim R11: reg-staged gather (3 global_load_dwordx4: lane l ->
//     row slot l>>3, 16B chunk (l&7)*16; slots 0..20 = 20 neighbors + center;
//     vidx via __shfl), ds_write_b128 stage, f16 window-sum consumer, 8-pt
//     MFMA batches, full-line store epilogue, 2x ping-pong pipeline, NSTG=2.

typedef __fp16 half2_t __attribute__((ext_vector_type(2)));
typedef __fp16 f16x4  __attribute__((ext_vector_type(4)));
typedef __fp16 f16x8  __attribute__((ext_vector_type(8)));
typedef float  f32x4  __attribute__((ext_vector_type(4)));
typedef unsigned int u32;
typedef unsigned short u16;

#if __has_builtin(__builtin_amdgcn_fdot2)
#define FDOT2(a, b, c) __builtin_amdgcn_fdot2((a), (b), (c), false)
#else
#define FDOT2(a, b, c) fmaf((float)((a)[0]), (float)((b)[0]), fmaf((float)((a)[1]), (float)((b)[1]), (c)))
#endif

namespace {
constexpr int N_    = 32768;
constexpr int K_    = 20;
constexpr int C_    = 64;
constexpr int O_    = 64;
constexpr int BLOCK = 256;                 // 4 waves
constexpr int WPB   = 4;

// ---- f16 MFMA pipeline config
constexpr int GRID_F16 = 1024;             // 4 blocks/CU exactly
constexpr int NSTG   = 2;                  // double-buffered stage (reg-pipelined)
constexpr int STAGEB = K_ * C_ * 2 + C_ * 2;           // 2688 B (20 rows + f16 center)
constexpr int ESTR   = 272;                // E row stride (256+16 -> conflict-free b128)
constexpr int EROWS  = 8;                  // MFMA batch of 8 points
constexpr int LDS_WIN = WPB * NSTG * STAGEB;           // 21504 B
constexpr int LDS_E   = WPB * EROWS * ESTR;            //  8704 B  (total 30208)
constexpr int WVB_F16 = (GRID_F16 / 8) * 2 * WPB;      // 1024 waves per batch
constexpr int CNT_F16 = N_ / WVB_F16;                  // 32 iters = 4 x 8-batch

// ---- f32 fallback (proven kernel) config
constexpr int GRID_F32 = 768;
constexpr int ROWS  = K_ + 1;
constexpr int WBUF  = ROWS * C_;
constexpr int WROW  = 132;
constexpr int WVB_F32 = (GRID_F32 / 8) * 2 * WPB;      // 768
}

// ---------------------------------------------------------------- pre-pass
__global__ __launch_bounds__(BLOCK) void cvt_f16_kernel(
    const float* __restrict__ x, __fp16* __restrict__ xh)
{
  const size_t i = ((size_t)blockIdx.x * BLOCK + threadIdx.x) * 4;
  const float4 v = *reinterpret_cast<const float4*>(x + i);
  f16x4 h;
  h[0] = (__fp16)v.x; h[1] = (__fp16)v.y; h[2] = (__fp16)v.z; h[3] = (__fp16)v.w;
  *reinterpret_cast<f16x4*>(xh + i) = h;
}

// ---------------------------------------------------------------- main (MFMA)
__global__ __launch_bounds__(BLOCK, 4) void edgeconv_mfma_kernel(
    const __fp16* __restrict__ xh,    // (B,N,C) f16 shadow (all gather + center)
    const int*    __restrict__ adj,   // (B,N,K)
    const float*  __restrict__ W,     // (O, 2C)
    const float*  __restrict__ bias,  // (O,)
    float*        __restrict__ out)   // (B,N,O)
{
  __shared__ __align__(16) char smem[LDS_WIN + LDS_E];  // 30208 B

  const int lane = threadIdx.x & 63;
  const int wid  = __builtin_amdgcn_readfirstlane((int)(threadIdx.x >> 6));
  const int l15  = lane & 15;
  const int lg   = lane >> 4;

  // ---- prologue: W -> per-lane B-fragments (f16), direct global loads.
  // B-frag(ot,kc): lane holds W[ot*16 + l15][kc*32 + lg*8 + j], j=0..7
  f16x8 wb[16];
#pragma unroll
  for (int ot = 0; ot < 4; ++ot) {
#pragma unroll
    for (int kc = 0; kc < 4; ++kc) {
      const float* wp_ = W + (ot * 16 + l15) * (2 * C_) + kc * 32 + lg * 8;
      const float4 f0 = *reinterpret_cast<const float4*>(wp_);
      const float4 f1 = *reinterpret_cast<const float4*>(wp_ + 4);
      uint4 q;
      q.x = __builtin_bit_cast(u32, __builtin_amdgcn_cvt_pkrtz(f0.x, f0.y));
      q.y = __builtin_bit_cast(u32, __builtin_amdgcn_cvt_pkrtz(f0.z, f0.w));
      q.z = __builtin_bit_cast(u32, __builtin_amdgcn_cvt_pkrtz(f1.x, f1.y));
      q.w = __builtin_bit_cast(u32, __builtin_amdgcn_cvt_pkrtz(f1.z, f1.w));
      wb[ot * 4 + kc] = __builtin_bit_cast(f16x8, q);
    }
  }
  float bl4[4];
#pragma unroll
  for (int ot = 0; ot < 4; ++ot) bl4[ot] = bias[ot * 16 + l15];

  // XCD<->batch partition: blockIdx%8 -> XCD; one batch per 2 XCD slots.
  // xh batch slice = 4 MB -> resident in that XCD's 4 MB L2.
  const int xslot = blockIdx.x & 7;
  const int batch = xslot >> 1;                                // 0..3
  const int group = ((blockIdx.x >> 3) << 1) | (xslot & 1);    // 0..255
  const int wv    = group * WPB + wid;                         // 0..1023 in batch
  const __fp16* xhb  = xh  + (size_t)batch * (N_ * C_);
  const int*    adjb = adj + (size_t)batch * N_ * K_;

  char* const ebase = smem + LDS_WIN + wid * (EROWS * ESTR);
  char* const sbase = smem + (size_t)wid * NSTG * STAGEB;

  // vidx: lane k<20 holds adj[n*20+k]; lanes >=20 hold n (center row).
  auto load_vidx = [&](int it) -> int {
    int n = wv + it * WVB_F16;
    n = (n < N_) ? n : 0;                        // tail clamp (garbage unused)
    int v = n;
    if (lane < K_) v = adjb[n * K_ + lane];
    return v;
  };

  // 3 global_load_dwordx4 nt: lane l -> row slot l>>3 (+8 per inst), 16B chunk
  // (l&7)*16. Slots 0..19 = neighbors, slot 20 = center; lanes>=40 of inst2
  // masked. nt = no L1 allocation (the experiment's single variable).
  auto load_stage = [&](int vidx, f16x8* D) {
    const int sub = lane >> 3;
    const int co  = (lane & 7) * 8;              // f16 elems within row
#pragma unroll
    for (int i = 0; i < 3; ++i) {
      const int row = __shfl(vidx, i * 8 + sub, 64);
      if (i < 2 || lane < 40)
        D[i] = __builtin_nontemporal_load(
            reinterpret_cast<const f16x8*>(xhb + (size_t)row * C_ + co));
    }
  };

  auto write_stage = [&](int st, const f16x8* D) {
    char* base = sbase + st * STAGEB;
    *reinterpret_cast<f16x8*>(base + lane * 16)        = D[0];
    *reinterpret_cast<f16x8*>(base + 1024 + lane * 16) = D[1];
    if (lane < 40)
      *reinterpret_cast<f16x8*>(base + 2048 + lane * 16) = D[2];
  };

  const float inv = 1.0f / (float)K_;

  auto consume = [&](int it) {
    // window sum: lane c owns channel c: flat f16[20c .. 20c+19] = 5x uint2
    const char* buf = sbase + (it & 1) * STAGEB;
    const uint2* wq = reinterpret_cast<const uint2*>(buf + 40 * lane);
    const uint2 v0 = wq[0], v1 = wq[1], v2 = wq[2], v3 = wq[3], v4 = wq[4];
    const half2_t kOnes = {(__fp16)1.0f, (__fp16)1.0f};
    float t0 = 0.f, t1 = 0.f;
    t0 = FDOT2(__builtin_bit_cast(half2_t, v0.x), kOnes, t0);
    t1 = FDOT2(__builtin_bit_cast(half2_t, v0.y), kOnes, t1);
    t0 = FDOT2(__builtin_bit_cast(half2_t, v1.x), kOnes, t0);
    t1 = FDOT2(__builtin_bit_cast(half2_t, v1.y), kOnes, t1);
    t0 = FDOT2(__builtin_bit_cast(half2_t, v2.x), kOnes, t0);
    t1 = FDOT2(__builtin_bit_cast(half2_t, v2.y), kOnes, t1);
    t0 = FDOT2(__builtin_bit_cast(half2_t, v3.x), kOnes, t0);
    t1 = FDOT2(__builtin_bit_cast(half2_t, v3.y), kOnes, t1);
    t0 = FDOT2(__builtin_bit_cast(half2_t, v4.x), kOnes, t0);
    t1 = FDOT2(__builtin_bit_cast(half2_t, v4.y), kOnes, t1);

    // center channel c (raw f16) -> xv; a = t/K - xv
    const u16 xraw = *reinterpret_cast<const u16*>(buf + K_ * C_ * 2 + 2 * lane);
    const float xv = (float)__builtin_bit_cast(__fp16, xraw);
    const float a  = fmaf(t0 + t1, inv, -xv);

    // E row (it&7): [a(64 f16) | x(64 f16)] -- two b16 writes, x is a raw copy
    char* erow = ebase + (it & 7) * ESTR;
    *reinterpret_cast<__fp16*>(erow + 2 * lane) = (__fp16)a;
    *reinterpret_cast<u16*>(erow + 2 * C_ + 2 * lane) = xraw;

    // ---- every 8 points: one MFMA batch (8 pts x 64 outs; rows 8-15 unused)
    if ((it & 7) == 7) {
      __builtin_amdgcn_wave_barrier();
      f16x8 af[4];
#pragma unroll
      for (int kc = 0; kc < 4; ++kc)
        af[kc] = *reinterpret_cast<const f16x8*>(ebase + (l15 & 7) * ESTR + kc * 64 + lg * 16);
      f32x4 acc[4];
#pragma unroll
      for (int ot = 0; ot < 4; ++ot) acc[ot] = f32x4{0.f, 0.f, 0.f, 0.f};
#pragma unroll
      for (int kc = 0; kc < 4; ++kc) {
#pragma unroll
        for (int ot = 0; ot < 4; ++ot)
          acc[ot] = __builtin_amdgcn_mfma_f32_16x16x32_f16(af[kc], wb[ot * 4 + kc],
                                                           acc[ot], 0, 0, 0);
      }
      // bias in regs, then transpose through the (now-free) E tile for
      // full-line stores. C layout: col = ot*16+l15, row = lg*4+r (rows 0-7 valid).
      __builtin_amdgcn_wave_barrier();
      if (lg < 2) {
#pragma unroll
        for (int ot = 0; ot < 4; ++ot)
#pragma unroll
          for (int r = 0; r < 4; ++r)
            *reinterpret_cast<float*>(ebase + (lg * 4 + r) * ESTR + (ot * 16 + l15) * 4)
                = acc[ot][r] + bl4[ot];
      }
      __builtin_amdgcn_wave_barrier();
      const f32x4 s0 = *reinterpret_cast<const f32x4*>(ebase + lg * ESTR + l15 * 16);
      const f32x4 s1 = *reinterpret_cast<const f32x4*>(ebase + (4 + lg) * ESTR + l15 * 16);
      __builtin_amdgcn_wave_barrier();
      // rows p = lg (s0) and 4+lg (s1); point = wv + (it-7+p)*WVB
      float* ob = out + ((size_t)batch * N_ + wv + (size_t)(it - 7) * WVB_F16) * O_;
      __builtin_nontemporal_store(s0,
          reinterpret_cast<f32x4*>(ob + (size_t)lg * WVB_F16 * O_ + l15 * 4));
      __builtin_nontemporal_store(s1,
          reinterpret_cast<f32x4*>(ob + (size_t)(4 + lg) * WVB_F16 * O_ + l15 * 4));
    }
  };

  // ---- software pipeline: loads 2 ahead (regs), stage written 1 ahead.
  f16x8 D0[3], D1[3];
  {
    const int vi0 = load_vidx(0);
    load_stage(vi0, D1);                 // data(0)
    const int vi1 = load_vidx(1);
    write_stage(0, D1);                  // stage0 <- data(0)
    load_stage(vi1, D0);                 // data(1) -> D0
  }
  int viA = load_vidx(2);                // vidx(2) in flight
  int viB = 0;

  auto step = [&](int it, f16x8* DA, f16x8* DB, int& vA, int& vB) {
    write_stage((it + 1) & 1, DA);       // stage data(it+1)  (waits its loads)
    load_stage(vA, DB);                  // issue data(it+2)  (waits vidx(it+2))
    vB = load_vidx(it + 3);              // issue vidx(it+3)
    __builtin_amdgcn_wave_barrier();
    consume(it);
  };

  for (int it = 0; it < CNT_F16; it += 2) {
    step(it,     D0, D1, viA, viB);
    step(it + 1, D1, D0, viB, viA);
  }
}

// ---------------------------------------------------------------- f32 fallback
// (proven kernel, used only if d_ws can't hold the 16 MB f16 shadow)
__global__ __launch_bounds__(BLOCK, 3) void edgeconv_f32_kernel(
    const float* __restrict__ x,
    const int*   __restrict__ adj,
    const float* __restrict__ W,
    const float* __restrict__ bias,
    float*       __restrict__ out)
{
  __shared__ __align__(16) float win2[WPB][2][WBUF];
  __shared__ __align__(16) float fbuf[WPB][2 * C_];
  __shared__ __align__(16) u32   hbuf[WPB][C_];

  const int lane = threadIdx.x & 63;
  const int wid  = __builtin_amdgcn_readfirstlane((int)(threadIdx.x >> 6));

  half2_t wp[64];
  {
    float* wstage = &win2[0][0][0];
    for (int i = threadIdx.x; i < O_ * 2 * C_; i += BLOCK)
      wstage[(i >> 7) * WROW + (i & 127)] = W[i];
    __syncthreads();
    const float2* wrow = reinterpret_cast<const float2*>(wstage + lane * WROW);
#pragma unroll
    for (int i = 0; i < 64; ++i) {
      const float2 f = wrow[i];
      wp[i] = __builtin_amdgcn_cvt_pkrtz(f.x, f.y);
    }
    __syncthreads();
  }
  const float bl = bias[lane];

  const int xslot = blockIdx.x & 7;
  const int batch = xslot >> 1;
  const int group = ((blockIdx.x >> 3) << 1) | (xslot & 1);
  const int wv    = group * WPB + wid;
  const int cnt   = (N_ - wv + WVB_F32 - 1) / WVB_F32;
  const float* xb   = x + (size_t)batch * (N_ * C_);
  const int*   adjb = adj + (size_t)batch * N_ * K_;

  int idx[K_];

  auto loadidx = [&](int n) {
    const int* ar = adjb + n * K_;
#pragma unroll
    for (int k = 0; k < K_; ++k) idx[k] = ar[k];
  };
  auto issue = [&](int n, int bsel) {
    auto ldsw = (__attribute__((address_space(3))) u32*)(&win2[wid][bsel][0]);
#pragma unroll
    for (int k = 0; k < K_; ++k) {
      const float* src = xb + idx[k] * C_ + lane;
      __builtin_amdgcn_global_load_lds(
          (const __attribute__((address_space(1))) u32*)src,
          ldsw + k * C_, 4, 0, 0);
    }
    const float* srcx = xb + n * C_ + lane;
    __builtin_amdgcn_global_load_lds(
        (const __attribute__((address_space(1))) u32*)srcx,
        ldsw + K_ * C_, 4, 0, 0);
  };

  loadidx(wv);
  issue(wv, 0);
  if (cnt > 1) loadidx(wv + WVB_F32);

  for (int it = 0; it < cnt; ++it) {
    const int n   = wv + it * WVB_F32;
    const int cur = it & 1;

    if (it + 1 < cnt) {
      issue(n + WVB_F32, cur ^ 1);
      asm volatile("s_waitcnt vmcnt(21)" ::: "memory");
    } else {
      asm volatile("s_waitcnt vmcnt(0)" ::: "memory");
    }
    __builtin_amdgcn_wave_barrier();

    if (it + 2 < cnt) loadidx(wv + (it + 2) * WVB_F32);

    const float* mywin = &win2[wid][cur][0];
    const float4* wq = reinterpret_cast<const float4*>(mywin + lane * K_);
    float t = 0.f;
#pragma unroll
    for (int s = 0; s < 5; ++s) {
      const float4 v = wq[s];
      t += (v.x + v.y) + (v.z + v.w);
    }
    const float xv = mywin[K_ * C_ + lane];

    fbuf[wid][lane]      = t * (1.f / K_) - xv;
    fbuf[wid][C_ + lane] = xv;
    const float2 pr = reinterpret_cast<const float2*>(fbuf[wid])[lane];
    hbuf[wid][lane] = __builtin_bit_cast(u32, __builtin_amdgcn_cvt_pkrtz(pr.x, pr.y));

    float acc0 = 0.f, acc1 = 0.f, acc2 = 0.f, acc3 = 0.f;
    const uint4* hb = reinterpret_cast<const uint4*>(hbuf[wid]);
#pragma unroll
    for (int i = 0; i < 16; ++i) {
      const uint4 q = hb[i];
      acc0 = FDOT2(__builtin_bit_cast(half2_t, q.x), wp[4 * i + 0], acc0);
      acc1 = FDOT2(__builtin_bit_cast(half2_t, q.y), wp[4 * i + 1], acc1);
      acc2 = FDOT2(__builtin_bit_cast(half2_t, q.z), wp[4 * i + 2], acc2);
      acc3 = FDOT2(__builtin_bit_cast(half2_t, q.w), wp[4 * i + 3], acc3);
    }

    out[((size_t)batch * N_ + n) * O_ + lane] = ((acc0 + acc1) + (acc2 + acc3)) + bl;
  }
}

extern "C" void kernel_launch(void* const* d_in, const int* in_sizes, int n_in,
                              void* d_out, int out_size, void* d_ws, size_t ws_size,
                              hipStream_t stream) {
  const float* x    = (const float*)d_in[0];
  const int*   adj  = (const int*)d_in[1];
  const float* W    = (const float*)d_in[2];
  const float* bias = (const float*)d_in[3];
  float* out = (float*)d_out;

  const size_t need = (size_t)4 * N_ * C_ * sizeof(__fp16);   // 16 MB
  if (d_ws != nullptr && ws_size >= need) {
    __fp16* xh = (__fp16*)d_ws;
    hipLaunchKernelGGL(cvt_f16_kernel, dim3((4 * N_ * C_) / (4 * BLOCK)), dim3(BLOCK),
                       0, stream, x, xh);
    hipLaunchKernelGGL(edgeconv_mfma_kernel, dim3(GRID_F16), dim3(BLOCK), 0, stream,
                       xh, adj, W, bias, out);
  } else {
    hipLaunchKernelGGL(edgeconv_f32_kernel, dim3(GRID_F32), dim3(BLOCK), 0, stream,
                       x, adj, W, bias, out);
  }
}

// Round 10
// 147.939 us; speedup vs baseline: 1.1335x; 1.1335x over previous
//
#include <hip/hip_runtime.h>

// EdgeConv, algebraically simplified:
//   out[p,o] = sum_c (t[p,c]/K - x[p,c])*W[o,c] + sum_c x[p,c]*W[o,64+c] + b[o]
//   t[p,c]   = sum_{kk=0..19} flat[p, 20c+kk],  flat[p,j] = x[b, adj[p,j>>6], j&63]
// R13 = R11 + SC0 (L1-bypass, L2-allocate) BUFFER gather loads.
//     Ladder: 21 scattered row-requests/pt costs ~14cyc/req/CU regardless of
//     inst count (R8b=R10=R11) and nearly regardless of bytes/row (R5 f32 vs
//     R6 f16 = 72 vs 64us). R12 (nt) broke L2 residency (FETCH 64->156MB,
//     83us) -> nt evicts at L2 too on gfx950. Model: L1 MSHR/miss-queue
//     occupancy (~30 reqs in flight/CU at ~450cyc loaded latency = 14cyc/req).
//     sc0 = agent-scope load: bypasses the non-coherent vL1 (no L1 MSHR/alloc)
//     but keeps L2 allocation -- the clean probe nt wasn't. Emitted via
//     llvm.amdgcn.raw.buffer.load.v4f32 with aux=1 (CK pattern); SRSRC over
//     the 4MB batch slice, 32-bit voffset (also kills 64-bit addr math).
//     Everything else verbatim R11: reg-staged gather (3 x16B loads: lane l ->
//     row slot l>>3, chunk (l&7)*16; slots 0..20 = 20 neighbors + center;
//     vidx via __shfl), ds_write_b128 stage, f16 window-sum consumer, 8-pt
//     MFMA batches, full-line store epilogue, 2x ping-pong pipeline, NSTG=2.

typedef __fp16 half2_t __attribute__((ext_vector_type(2)));
typedef __fp16 f16x4  __attribute__((ext_vector_type(4)));
typedef __fp16 f16x8  __attribute__((ext_vector_type(8)));
typedef float  f32x4  __attribute__((ext_vector_type(4)));
typedef int    i32x4  __attribute__((ext_vector_type(4)));
typedef unsigned int u32;
typedef unsigned short u16;

// raw buffer load with explicit cache policy (cpol bit0 = sc0 on gfx950)
__device__ f32x4 llvm_amdgcn_raw_buffer_load_v4f32(
    i32x4 srsrc, u32 voffset, u32 soffset, int cpol)
    __asm("llvm.amdgcn.raw.buffer.load.v4f32");

#if __has_builtin(__builtin_amdgcn_fdot2)
#define FDOT2(a, b, c) __builtin_amdgcn_fdot2((a), (b), (c), false)
#else
#define FDOT2(a, b, c) fmaf((float)((a)[0]), (float)((b)[0]), fmaf((float)((a)[1]), (float)((b)[1]), (c)))
#endif

namespace {
constexpr int N_    = 32768;
constexpr int K_    = 20;
constexpr int C_    = 64;
constexpr int O_    = 64;
constexpr int BLOCK = 256;                 // 4 waves
constexpr int WPB   = 4;

// ---- f16 MFMA pipeline config
constexpr int GRID_F16 = 1024;             // 4 blocks/CU exactly
constexpr int NSTG   = 2;                  // double-buffered stage (reg-pipelined)
constexpr int STAGEB = K_ * C_ * 2 + C_ * 2;           // 2688 B (20 rows + f16 center)
constexpr int ESTR   = 272;                // E row stride (256+16 -> conflict-free b128)
constexpr int EROWS  = 8;                  // MFMA batch of 8 points
constexpr int LDS_WIN = WPB * NSTG * STAGEB;           // 21504 B
constexpr int LDS_E   = WPB * EROWS * ESTR;            //  8704 B  (total 30208)
constexpr int WVB_F16 = (GRID_F16 / 8) * 2 * WPB;      // 1024 waves per batch
constexpr int CNT_F16 = N_ / WVB_F16;                  // 32 iters = 4 x 8-batch

// ---- f32 fallback (proven kernel) config
constexpr int GRID_F32 = 768;
constexpr int ROWS  = K_ + 1;
constexpr int WBUF  = ROWS * C_;
constexpr int WROW  = 132;
constexpr int WVB_F32 = (GRID_F32 / 8) * 2 * WPB;      // 768
}

// ---------------------------------------------------------------- pre-pass
__global__ __launch_bounds__(BLOCK) void cvt_f16_kernel(
    const float* __restrict__ x, __fp16* __restrict__ xh)
{
  const size_t i = ((size_t)blockIdx.x * BLOCK + threadIdx.x) * 4;
  const float4 v = *reinterpret_cast<const float4*>(x + i);
  f16x4 h;
  h[0] = (__fp16)v.x; h[1] = (__fp16)v.y; h[2] = (__fp16)v.z; h[3] = (__fp16)v.w;
  *reinterpret_cast<f16x4*>(xh + i) = h;
}

// ---------------------------------------------------------------- main (MFMA)
__global__ __launch_bounds__(BLOCK, 4) void edgeconv_mfma_kernel(
    const __fp16* __restrict__ xh,    // (B,N,C) f16 shadow (all gather + center)
    const int*    __restrict__ adj,   // (B,N,K)
    const float*  __restrict__ W,     // (O, 2C)
    const float*  __restrict__ bias,  // (O,)
    float*        __restrict__ out)   // (B,N,O)
{
  __shared__ __align__(16) char smem[LDS_WIN + LDS_E];  // 30208 B

  const int lane = threadIdx.x & 63;
  const int wid  = __builtin_amdgcn_readfirstlane((int)(threadIdx.x >> 6));
  const int l15  = lane & 15;
  const int lg   = lane >> 4;

  // ---- prologue: W -> per-lane B-fragments (f16), direct global loads.
  // B-frag(ot,kc): lane holds W[ot*16 + l15][kc*32 + lg*8 + j], j=0..7
  f16x8 wb[16];
#pragma unroll
  for (int ot = 0; ot < 4; ++ot) {
#pragma unroll
    for (int kc = 0; kc < 4; ++kc) {
      const float* wp_ = W + (ot * 16 + l15) * (2 * C_) + kc * 32 + lg * 8;
      const float4 f0 = *reinterpret_cast<const float4*>(wp_);
      const float4 f1 = *reinterpret_cast<const float4*>(wp_ + 4);
      uint4 q;
      q.x = __builtin_bit_cast(u32, __builtin_amdgcn_cvt_pkrtz(f0.x, f0.y));
      q.y = __builtin_bit_cast(u32, __builtin_amdgcn_cvt_pkrtz(f0.z, f0.w));
      q.z = __builtin_bit_cast(u32, __builtin_amdgcn_cvt_pkrtz(f1.x, f1.y));
      q.w = __builtin_bit_cast(u32, __builtin_amdgcn_cvt_pkrtz(f1.z, f1.w));
      wb[ot * 4 + kc] = __builtin_bit_cast(f16x8, q);
    }
  }
  float bl4[4];
#pragma unroll
  for (int ot = 0; ot < 4; ++ot) bl4[ot] = bias[ot * 16 + l15];

  // XCD<->batch partition: blockIdx%8 -> XCD; one batch per 2 XCD slots.
  // xh batch slice = 4 MB -> resident in that XCD's 4 MB L2.
  const int xslot = blockIdx.x & 7;
  const int batch = xslot >> 1;                                // 0..3
  const int group = ((blockIdx.x >> 3) << 1) | (xslot & 1);    // 0..255
  const int wv    = group * WPB + wid;                         // 0..1023 in batch
  const __fp16* xhb  = xh  + (size_t)batch * (N_ * C_);
  const int*    adjb = adj + (size_t)batch * N_ * K_;

  // SRSRC over the 4 MB xh batch slice (stride=0, raw dword, bounds = bytes)
  i32x4 srsrc;
  {
    union { const __fp16* p; u32 w[2]; } a; a.p = xhb;
    srsrc[0] = (int)a.w[0];
    srsrc[1] = (int)(a.w[1] & 0xFFFFu);
    srsrc[2] = (int)(N_ * C_ * 2);               // num_records = 4 MB
    srsrc[3] = 0x00020000;
  }

  char* const ebase = smem + LDS_WIN + wid * (EROWS * ESTR);
  char* const sbase = smem + (size_t)wid * NSTG * STAGEB;

  // vidx: lane k<20 holds adj[n*20+k]; lanes >=20 hold n (center row).
  auto load_vidx = [&](int it) -> int {
    int n = wv + it * WVB_F16;
    n = (n < N_) ? n : 0;                        // tail clamp (garbage unused)
    int v = n;
    if (lane < K_) v = adjb[n * K_ + lane];
    return v;
  };

  // 3 buffer_load_dwordx4 sc0: lane l -> row slot l>>3 (+8 per inst), 16B
  // chunk (l&7)*16. Slots 0..19 = neighbors, slot 20 = center; lanes>=40 of
  // inst2 masked. sc0 = agent scope: no vL1 allocation/MSHR, L2 kept.
  auto load_stage = [&](int vidx, f16x8* D) {
    const int sub = lane >> 3;
    const u32 co  = (u32)(lane & 7) * 16u;       // byte offset within row
#pragma unroll
    for (int i = 0; i < 3; ++i) {
      const int row = __shfl(vidx, i * 8 + sub, 64);
      if (i < 2 || lane < 40) {
        const u32 voff = (u32)row * (u32)(C_ * 2) + co;
        D[i] = __builtin_bit_cast(f16x8,
            llvm_amdgcn_raw_buffer_load_v4f32(srsrc, voff, 0u, 1 /*sc0*/));
      }
    }
  };

  auto write_stage = [&](int st, const f16x8* D) {
    char* base = sbase + st * STAGEB;
    *reinterpret_cast<f16x8*>(base + lane * 16)        = D[0];
    *reinterpret_cast<f16x8*>(base + 1024 + lane * 16) = D[1];
    if (lane < 40)
      *reinterpret_cast<f16x8*>(base + 2048 + lane * 16) = D[2];
  };

  const float inv = 1.0f / (float)K_;

  auto consume = [&](int it) {
    // window sum: lane c owns channel c: flat f16[20c .. 20c+19] = 5x uint2
    const char* buf = sbase + (it & 1) * STAGEB;
    const uint2* wq = reinterpret_cast<const uint2*>(buf + 40 * lane);
    const uint2 v0 = wq[0], v1 = wq[1], v2 = wq[2], v3 = wq[3], v4 = wq[4];
    const half2_t kOnes = {(__fp16)1.0f, (__fp16)1.0f};
    float t0 = 0.f, t1 = 0.f;
    t0 = FDOT2(__builtin_bit_cast(half2_t, v0.x), kOnes, t0);
    t1 = FDOT2(__builtin_bit_cast(half2_t, v0.y), kOnes, t1);
    t0 = FDOT2(__builtin_bit_cast(half2_t, v1.x), kOnes, t0);
    t1 = FDOT2(__builtin_bit_cast(half2_t, v1.y), kOnes, t1);
    t0 = FDOT2(__builtin_bit_cast(half2_t, v2.x), kOnes, t0);
    t1 = FDOT2(__builtin_bit_cast(half2_t, v2.y), kOnes, t1);
    t0 = FDOT2(__builtin_bit_cast(half2_t, v3.x), kOnes, t0);
    t1 = FDOT2(__builtin_bit_cast(half2_t, v3.y), kOnes, t1);
    t0 = FDOT2(__builtin_bit_cast(half2_t, v4.x), kOnes, t0);
    t1 = FDOT2(__builtin_bit_cast(half2_t, v4.y), kOnes, t1);

    // center channel c (raw f16) -> xv; a = t/K - xv
    const u16 xraw = *reinterpret_cast<const u16*>(buf + K_ * C_ * 2 + 2 * lane);
    const float xv = (float)__builtin_bit_cast(__fp16, xraw);
    const float a  = fmaf(t0 + t1, inv, -xv);

    // E row (it&7): [a(64 f16) | x(64 f16)] -- two b16 writes, x is a raw copy
    char* erow = ebase + (it & 7) * ESTR;
    *reinterpret_cast<__fp16*>(erow + 2 * lane) = (__fp16)a;
    *reinterpret_cast<u16*>(erow + 2 * C_ + 2 * lane) = xraw;

    // ---- every 8 points: one MFMA batch (8 pts x 64 outs; rows 8-15 unused)
    if ((it & 7) == 7) {
      __builtin_amdgcn_wave_barrier();
      f16x8 af[4];
#pragma unroll
      for (int kc = 0; kc < 4; ++kc)
        af[kc] = *reinterpret_cast<const f16x8*>(ebase + (l15 & 7) * ESTR + kc * 64 + lg * 16);
      f32x4 acc[4];
#pragma unroll
      for (int ot = 0; ot < 4; ++ot) acc[ot] = f32x4{0.f, 0.f, 0.f, 0.f};
#pragma unroll
      for (int kc = 0; kc < 4; ++kc) {
#pragma unroll
        for (int ot = 0; ot < 4; ++ot)
          acc[ot] = __builtin_amdgcn_mfma_f32_16x16x32_f16(af[kc], wb[ot * 4 + kc],
                                                           acc[ot], 0, 0, 0);
      }
      // bias in regs, then transpose through the (now-free) E tile for
      // full-line stores. C layout: col = ot*16+l15, row = lg*4+r (rows 0-7 valid).
      __builtin_amdgcn_wave_barrier();
      if (lg < 2) {
#pragma unroll
        for (int ot = 0; ot < 4; ++ot)
#pragma unroll
          for (int r = 0; r < 4; ++r)
            *reinterpret_cast<float*>(ebase + (lg * 4 + r) * ESTR + (ot * 16 + l15) * 4)
                = acc[ot][r] + bl4[ot];
      }
      __builtin_amdgcn_wave_barrier();
      const f32x4 s0 = *reinterpret_cast<const f32x4*>(ebase + lg * ESTR + l15 * 16);
      const f32x4 s1 = *reinterpret_cast<const f32x4*>(ebase + (4 + lg) * ESTR + l15 * 16);
      __builtin_amdgcn_wave_barrier();
      // rows p = lg (s0) and 4+lg (s1); point = wv + (it-7+p)*WVB
      float* ob = out + ((size_t)batch * N_ + wv + (size_t)(it - 7) * WVB_F16) * O_;
      __builtin_nontemporal_store(s0,
          reinterpret_cast<f32x4*>(ob + (size_t)lg * WVB_F16 * O_ + l15 * 4));
      __builtin_nontemporal_store(s1,
          reinterpret_cast<f32x4*>(ob + (size_t)(4 + lg) * WVB_F16 * O_ + l15 * 4));
    }
  };

  // ---- software pipeline: loads 2 ahead (regs), stage written 1 ahead.
  f16x8 D0[3], D1[3];
  {
    const int vi0 = load_vidx(0);
    load_stage(vi0, D1);                 // data(0)
    const int vi1 = load_vidx(1);
    write_stage(0, D1);                  // stage0 <- data(0)
    load_stage(vi1, D0);                 // data(1) -> D0
  }
  int viA = load_vidx(2);                // vidx(2) in flight
  int viB = 0;

  auto step = [&](int it, f16x8* DA, f16x8* DB, int& vA, int& vB) {
    write_stage((it + 1) & 1, DA);       // stage data(it+1)  (waits its loads)
    load_stage(vA, DB);                  // issue data(it+2)  (waits vidx(it+2))
    vB = load_vidx(it + 3);              // issue vidx(it+3)
    __builtin_amdgcn_wave_barrier();
    consume(it);
  };

  for (int it = 0; it < CNT_F16; it += 2) {
    step(it,     D0, D1, viA, viB);
    step(it + 1, D1, D0, viB, viA);
  }
}

// ---------------------------------------------------------------- f32 fallback
// (proven kernel, used only if d_ws can't hold the 16 MB f16 shadow)
__global__ __launch_bounds__(BLOCK, 3) void edgeconv_f32_kernel(
    const float* __restrict__ x,
    const int*   __restrict__ adj,
    const float* __restrict__ W,
    const float* __restrict__ bias,
    float*       __restrict__ out)
{
  __shared__ __align__(16) float win2[WPB][2][WBUF];
  __shared__ __align__(16) float fbuf[WPB][2 * C_];
  __shared__ __align__(16) u32   hbuf[WPB][C_];

  const int lane = threadIdx.x & 63;
  const int wid  = __builtin_amdgcn_readfirstlane((int)(threadIdx.x >> 6));

  half2_t wp[64];
  {
    float* wstage = &win2[0][0][0];
    for (int i = threadIdx.x; i < O_ * 2 * C_; i += BLOCK)
      wstage[(i >> 7) * WROW + (i & 127)] = W[i];
    __syncthreads();
    const float2* wrow = reinterpret_cast<const float2*>(wstage + lane * WROW);
#pragma unroll
    for (int i = 0; i < 64; ++i) {
      const float2 f = wrow[i];
      wp[i] = __builtin_amdgcn_cvt_pkrtz(f.x, f.y);
    }
    __syncthreads();
  }
  const float bl = bias[lane];

  const int xslot = blockIdx.x & 7;
  const int batch = xslot >> 1;
  const int group = ((blockIdx.x >> 3) << 1) | (xslot & 1);
  const int wv    = group * WPB + wid;
  const int cnt   = (N_ - wv + WVB_F32 - 1) / WVB_F32;
  const float* xb   = x + (size_t)batch * (N_ * C_);
  const int*   adjb = adj + (size_t)batch * N_ * K_;

  int idx[K_];

  auto loadidx = [&](int n) {
    const int* ar = adjb + n * K_;
#pragma unroll
    for (int k = 0; k < K_; ++k) idx[k] = ar[k];
  };
  auto issue = [&](int n, int bsel) {
    auto ldsw = (__attribute__((address_space(3))) u32*)(&win2[wid][bsel][0]);
#pragma unroll
    for (int k = 0; k < K_; ++k) {
      const float* src = xb + idx[k] * C_ + lane;
      __builtin_amdgcn_global_load_lds(
          (const __attribute__((address_space(1))) u32*)src,
          ldsw + k * C_, 4, 0, 0);
    }
    const float* srcx = xb + n * C_ + lane;
    __builtin_amdgcn_global_load_lds(
        (const __attribute__((address_space(1))) u32*)srcx,
        ldsw + K_ * C_, 4, 0, 0);
  };

  loadidx(wv);
  issue(wv, 0);
  if (cnt > 1) loadidx(wv + WVB_F32);

  for (int it = 0; it < cnt; ++it) {
    const int n   = wv + it * WVB_F32;
    const int cur = it & 1;

    if (it + 1 < cnt) {
      issue(n + WVB_F32, cur ^ 1);
      asm volatile("s_waitcnt vmcnt(21)" ::: "memory");
    } else {
      asm volatile("s_waitcnt vmcnt(0)" ::: "memory");
    }
    __builtin_amdgcn_wave_barrier();

    if (it + 2 < cnt) loadidx(wv + (it + 2) * WVB_F32);

    const float* mywin = &win2[wid][cur][0];
    const float4* wq = reinterpret_cast<const float4*>(mywin + lane * K_);
    float t = 0.f;
#pragma unroll
    for (int s = 0; s < 5; ++s) {
      const float4 v = wq[s];
      t += (v.x + v.y) + (v.z + v.w);
    }
    const float xv = mywin[K_ * C_ + lane];

    fbuf[wid][lane]      = t * (1.f / K_) - xv;
    fbuf[wid][C_ + lane] = xv;
    const float2 pr = reinterpret_cast<const float2*>(fbuf[wid])[lane];
    hbuf[wid][lane] = __builtin_bit_cast(u32, __builtin_amdgcn_cvt_pkrtz(pr.x, pr.y));

    float acc0 = 0.f, acc1 = 0.f, acc2 = 0.f, acc3 = 0.f;
    const uint4* hb = reinterpret_cast<const uint4*>(hbuf[wid]);
#pragma unroll
    for (int i = 0; i < 16; ++i) {
      const uint4 q = hb[i];
      acc0 = FDOT2(__builtin_bit_cast(half2_t, q.x), wp[4 * i + 0], acc0);
      acc1 = FDOT2(__builtin_bit_cast(half2_t, q.y), wp[4 * i + 1], acc1);
      acc2 = FDOT2(__builtin_bit_cast(half2_t, q.z), wp[4 * i + 2], acc2);
      acc3 = FDOT2(__builtin_bit_cast(half2_t, q.w), wp[4 * i + 3], acc3);
    }

    out[((size_t)batch * N_ + n) * O_ + lane] = ((acc0 + acc1) + (acc2 + acc3)) + bl;
  }
}

extern "C" void kernel_launch(void* const* d_in, const int* in_sizes, int n_in,
                              void* d_out, int out_size, void* d_ws, size_t ws_size,
                              hipStream_t stream) {
  const float* x    = (const float*)d_in[0];
  const int*   adj  = (const int*)d_in[1];
  const float* W    = (const float*)d_in[2];
  const float* bias = (const float*)d_in[3];
  float* out = (float*)d_out;

  const size_t need = (size_t)4 * N_ * C_ * sizeof(__fp16);   // 16 MB
  if (d_ws != nullptr && ws_size >= need) {
    __fp16* xh = (__fp16*)d_ws;
    hipLaunchKernelGGL(cvt_f16_kernel, dim3((4 * N_ * C_) / (4 * BLOCK)), dim3(BLOCK),
                       0, stream, x, xh);
    hipLaunchKernelGGL(edgeconv_mfma_kernel, dim3(GRID_F16), dim3(BLOCK), 0, stream,
                       xh, adj, W, bias, out);
  } else {
    hipLaunchKernelGGL(edgeconv_f32_kernel, dim3(GRID_F32), dim3(BLOCK), 0, stream,
                       x, adj, W, bias, out);
  }
}